// Round 3
// baseline (3881.413 us; speedup 1.0000x reference)
//
#include <hip/hip_runtime.h>

#define BQ 8
#define NPTS 16384
#define CFEAT 64
#define NPOINT 1024
#define NSAMPLE 32
#define RADIUS2 0.04f

// ------------------------------------------------------------------
// Furthest point sampling: one block per batch, 1024 threads, 16 pts/thread
// in registers. Writes new_xyz (B, NPOINT, 3) directly into d_out.
// fp contract OFF so fp32 matches numpy's unfused order (argmax stability).
// ------------------------------------------------------------------
__global__ __launch_bounds__(1024) void fps_kernel(const float* __restrict__ xyz,
                                                   float* __restrict__ newxyz) {
#pragma clang fp contract(off)
  const int b = blockIdx.x;
  const int t = threadIdx.x;
  const float* xb = xyz + (size_t)b * NPTS * 3;
  float px[16], py[16], pz[16], dist[16];
#pragma unroll
  for (int k = 0; k < 16; ++k) {
    int p = k * 1024 + t;
    px[k] = xb[p * 3 + 0];
    py[k] = xb[p * 3 + 1];
    pz[k] = xb[p * 3 + 2];
    dist[k] = 1e10f;
  }
  __shared__ float s_last[3];
  __shared__ float s_val[16];
  __shared__ int s_idx[16];
  if (t == 0) {
    float x0 = xb[0], y0 = xb[1], z0 = xb[2];
    s_last[0] = x0; s_last[1] = y0; s_last[2] = z0;
    float* o = newxyz + (size_t)b * NPOINT * 3;
    o[0] = x0; o[1] = y0; o[2] = z0;
  }
  __syncthreads();
  for (int j = 1; j < NPOINT; ++j) {
    const float lx = s_last[0], ly = s_last[1], lz = s_last[2];
    float bestv = -1.0f;
    int bestk = 0;
#pragma unroll
    for (int k = 0; k < 16; ++k) {
      float dx = px[k] - lx, dy = py[k] - ly, dz = pz[k] - lz;
      float d = dx * dx + dy * dy;
      d = d + dz * dz;
      float nd = fminf(dist[k], d);
      dist[k] = nd;
      if (nd > bestv) { bestv = nd; bestk = k; }  // strict > keeps smallest k
    }
    int besti = bestk * 1024 + t;
    // wave-64 argmax reduction, smallest-index tie break
#pragma unroll
    for (int off = 1; off < 64; off <<= 1) {
      float ov = __shfl_xor(bestv, off);
      int oi = __shfl_xor(besti, off);
      if (ov > bestv || (ov == bestv && oi < besti)) { bestv = ov; besti = oi; }
    }
    if ((t & 63) == 0) { s_val[t >> 6] = bestv; s_idx[t >> 6] = besti; }
    __syncthreads();
    if (t == 0) {
      float v = s_val[0]; int wi = s_idx[0];
      for (int w = 1; w < 16; ++w) {
        float ov = s_val[w]; int oi = s_idx[w];
        if (ov > v || (ov == v && oi < wi)) { v = ov; wi = oi; }
      }
      const float* p = xb + (size_t)wi * 3;
      float wx = p[0], wy = p[1], wz = p[2];
      s_last[0] = wx; s_last[1] = wy; s_last[2] = wz;
      float* o = newxyz + ((size_t)b * NPOINT + j) * 3;
      o[0] = wx; o[1] = wy; o[2] = wz;
    }
    __syncthreads();
  }
}

// ------------------------------------------------------------------
// Ball query: 1 wave per query, 4 queries per 256-thread block.
// Scans all N points in index order via LDS tiles; ballot-compacts the
// first 32 indices with d2 <= r^2; pads remainder with first index.
// ------------------------------------------------------------------
__global__ __launch_bounds__(256) void ballquery_kernel(const float* __restrict__ xyz,
                                                        const float* __restrict__ newxyz,
                                                        int* __restrict__ idxout) {
#pragma clang fp contract(off)
  const int blk = blockIdx.x;
  const int b = blk >> 8;  // 256 blocks per batch
  const int t = threadIdx.x;
  const int w = t >> 6;
  const int lane = t & 63;
  const int q = ((blk & 255) << 2) | w;
  const int g = b * NPOINT + q;
  const float* xb = xyz + (size_t)b * NPTS * 3;
  const float qx = newxyz[(size_t)g * 3 + 0];
  const float qy = newxyz[(size_t)g * 3 + 1];
  const float qz = newxyz[(size_t)g * 3 + 2];
  __shared__ __align__(16) float lds[2048 * 3];
  int total = 0;
  int first = 0;
  const unsigned long long ltmask = (1ull << lane) - 1ull;
  for (int T = 0; T < 8; ++T) {
    __syncthreads();
    const float4* src = (const float4*)(xb + (size_t)T * 2048 * 3);
#pragma unroll
    for (int k = 0; k < 6; ++k) ((float4*)lds)[t + 256 * k] = src[t + 256 * k];
    __syncthreads();
    if (total < NSAMPLE) {
      for (int c = 0; c < 32; ++c) {
        const int il = (c << 6) | lane;
        float dx = lds[il * 3 + 0] - qx;
        float dy = lds[il * 3 + 1] - qy;
        float dz = lds[il * 3 + 2] - qz;
        float d2 = dx * dx + dy * dy;
        d2 = d2 + dz * dz;
        const bool within = d2 <= RADIUS2;
        const unsigned long long mask = __ballot(within);
        if (total == 0 && mask != 0ull)
          first = (T << 11) | (c << 6) | (__ffsll((unsigned long long)mask) - 1);
        if (within) {
          int pos = total + __popcll(mask & ltmask);
          if (pos < NSAMPLE) idxout[(size_t)g * NSAMPLE + pos] = (T << 11) | il;
        }
        total += __popcll(mask);
        if (total >= NSAMPLE) break;
      }
    }
  }
  if (total < NSAMPLE) {
    if (lane >= total && lane < NSAMPLE) idxout[(size_t)g * NSAMPLE + lane] = first;
  }
}

// ------------------------------------------------------------------
// features (B, C, N) -> featT (B, N, C) so the gather reads 256B rows.
// ------------------------------------------------------------------
__global__ __launch_bounds__(256) void transpose_kernel(const float* __restrict__ feat,
                                                        float* __restrict__ featT) {
  __shared__ float tile[64][65];
  const int b = blockIdx.y;
  const int n0 = blockIdx.x * 64;
  const int t = threadIdx.x;
  const int col = t & 63;
  const int row = t >> 6;
#pragma unroll
  for (int k = 0; k < 16; ++k) {
    int c = k * 4 + row;
    tile[c][col] = feat[((size_t)b * CFEAT + c) * NPTS + n0 + col];
  }
  __syncthreads();
#pragma unroll
  for (int k = 0; k < 16; ++k) {
    int nl = k * 4 + row;
    featT[((size_t)b * NPTS + n0 + nl) * CFEAT + col] = tile[col][nl];
  }
}

// ------------------------------------------------------------------
// Transpose the tiny weight matrices once: W*T[c][o] = W*[o][c]
// ------------------------------------------------------------------
__global__ void prep_wt(const float* __restrict__ W1, const float* __restrict__ W2,
                        const float* __restrict__ W3, float* __restrict__ WT) {
  int t = blockIdx.x * blockDim.x + threadIdx.x;
  int stride = gridDim.x * blockDim.x;
  float* W1T = WT;                    // 67 x 64
  float* W2T = WT + 67 * 64;          // 64 x 64
  float* W3T = WT + 67 * 64 + 64 * 64;// 64 x 128
  for (int i = t; i < 64 * 67; i += stride) { int o = i / 67, c = i - o * 67; W1T[c * 64 + o] = W1[i]; }
  for (int i = t; i < 64 * 64; i += stride) { int o = i >> 6, c = i & 63; W2T[c * 64 + o] = W2[i]; }
  for (int i = t; i < 128 * 64; i += stride) { int o = i >> 6, c = i & 63; W3T[c * 128 + o] = W3[i]; }
}

// ------------------------------------------------------------------
// Gather + 3-layer pointwise MLP + max over 32 samples. One block per
// group (b,q): 256 threads = 32 samples x 8 lanes. Hidden activations
// staged in LDS (padded strides 69/132 -> conflict-free). Weights are
// read from global (66KB, L1/L2-resident).
// ------------------------------------------------------------------
template <bool USE_FEATT>
__global__ __launch_bounds__(256) void mlp_kernel(const float* __restrict__ xyz,
                                                  const float* __restrict__ feat,
                                                  const float* __restrict__ featT,
                                                  const float* __restrict__ newxyz,
                                                  const int* __restrict__ idx,
                                                  const float* __restrict__ WT,
                                                  const float* __restrict__ b1,
                                                  const float* __restrict__ b2,
                                                  const float* __restrict__ b3,
                                                  float* __restrict__ outfeat) {
  const int g = blockIdx.x;
  const int b = g >> 10;
  const int q = g & 1023;
  const int t = threadIdx.x;
  const int s = t >> 3;
  const int u = t & 7;
  __shared__ float in_s[32][69];
  __shared__ float h1_s[32][69];
  __shared__ float h2_s[32][69];
  __shared__ float h3_s[32][132];
  const float* W1T = WT;
  const float* W2T = WT + 67 * 64;
  const float* W3T = WT + 67 * 64 + 64 * 64;

  const int gi = idx[(size_t)g * NSAMPLE + s];
  if (u == 0) {
    const float* p = xyz + ((size_t)b * NPTS + gi) * 3;
    const float* c = newxyz + (size_t)g * 3;
    in_s[s][0] = p[0] - c[0];
    in_s[s][1] = p[1] - c[1];
    in_s[s][2] = p[2] - c[2];
  }
  if (USE_FEATT) {
    const float* fr = featT + ((size_t)b * NPTS + gi) * CFEAT + u * 8;
    float4 a = *(const float4*)fr;
    float4 c4 = *(const float4*)(fr + 4);
    in_s[s][3 + u * 8 + 0] = a.x;  in_s[s][3 + u * 8 + 1] = a.y;
    in_s[s][3 + u * 8 + 2] = a.z;  in_s[s][3 + u * 8 + 3] = a.w;
    in_s[s][3 + u * 8 + 4] = c4.x; in_s[s][3 + u * 8 + 5] = c4.y;
    in_s[s][3 + u * 8 + 6] = c4.z; in_s[s][3 + u * 8 + 7] = c4.w;
  } else {
#pragma unroll
    for (int k = 0; k < 8; ++k)
      in_s[s][3 + u * 8 + k] = feat[((size_t)b * CFEAT + u * 8 + k) * NPTS + gi];
  }
  __syncthreads();
  {  // layer 1: 67 -> 64
    float acc[8];
    const int o0 = u * 8;
#pragma unroll
    for (int k = 0; k < 8; ++k) acc[k] = b1[o0 + k];
    for (int c = 0; c < 67; ++c) {
      float x = in_s[s][c];
      const float* wp = W1T + c * 64 + o0;
      float4 w0 = *(const float4*)wp;
      float4 w1 = *(const float4*)(wp + 4);
      acc[0] += w0.x * x; acc[1] += w0.y * x; acc[2] += w0.z * x; acc[3] += w0.w * x;
      acc[4] += w1.x * x; acc[5] += w1.y * x; acc[6] += w1.z * x; acc[7] += w1.w * x;
    }
#pragma unroll
    for (int k = 0; k < 8; ++k) h1_s[s][o0 + k] = fmaxf(acc[k], 0.0f);
  }
  __syncthreads();
  {  // layer 2: 64 -> 64
    float acc[8];
    const int o0 = u * 8;
#pragma unroll
    for (int k = 0; k < 8; ++k) acc[k] = b2[o0 + k];
    for (int c = 0; c < 64; ++c) {
      float x = h1_s[s][c];
      const float* wp = W2T + c * 64 + o0;
      float4 w0 = *(const float4*)wp;
      float4 w1 = *(const float4*)(wp + 4);
      acc[0] += w0.x * x; acc[1] += w0.y * x; acc[2] += w0.z * x; acc[3] += w0.w * x;
      acc[4] += w1.x * x; acc[5] += w1.y * x; acc[6] += w1.z * x; acc[7] += w1.w * x;
    }
#pragma unroll
    for (int k = 0; k < 8; ++k) h2_s[s][o0 + k] = fmaxf(acc[k], 0.0f);
  }
  __syncthreads();
  {  // layer 3: 64 -> 128
    float acc[16];
    const int o0 = u * 16;
#pragma unroll
    for (int k = 0; k < 16; ++k) acc[k] = b3[o0 + k];
    for (int c = 0; c < 64; ++c) {
      float x = h2_s[s][c];
      const float* wp = W3T + c * 128 + o0;
      float4 w0 = *(const float4*)wp;
      float4 w1 = *(const float4*)(wp + 4);
      float4 w2 = *(const float4*)(wp + 8);
      float4 w3 = *(const float4*)(wp + 12);
      acc[0] += w0.x * x;  acc[1] += w0.y * x;  acc[2] += w0.z * x;  acc[3] += w0.w * x;
      acc[4] += w1.x * x;  acc[5] += w1.y * x;  acc[6] += w1.z * x;  acc[7] += w1.w * x;
      acc[8] += w2.x * x;  acc[9] += w2.y * x;  acc[10] += w2.z * x; acc[11] += w2.w * x;
      acc[12] += w3.x * x; acc[13] += w3.y * x; acc[14] += w3.z * x; acc[15] += w3.w * x;
    }
#pragma unroll
    for (int k = 0; k < 16; ++k) h3_s[s][o0 + k] = fmaxf(acc[k], 0.0f);
  }
  __syncthreads();
  if (t < 128) {
    float m = h3_s[0][t];
#pragma unroll 4
    for (int ss = 1; ss < 32; ++ss) m = fmaxf(m, h3_s[ss][t]);
    outfeat[((size_t)b * 128 + t) * NPOINT + q] = m;
  }
}

extern "C" void kernel_launch(void* const* d_in, const int* in_sizes, int n_in,
                              void* d_out, int out_size, void* d_ws, size_t ws_size,
                              hipStream_t stream) {
  const float* xyz = (const float*)d_in[0];
  const float* features = (const float*)d_in[1];
  const float* W1 = (const float*)d_in[2];
  const float* b1 = (const float*)d_in[3];
  const float* W2 = (const float*)d_in[4];
  const float* b2 = (const float*)d_in[5];
  const float* W3 = (const float*)d_in[6];
  const float* b3 = (const float*)d_in[7];
  float* out_newxyz = (float*)d_out;                               // B*NPOINT*3
  float* out_feat = (float*)d_out + (size_t)BQ * NPOINT * 3;       // B*128*NPOINT

  char* ws = (char*)d_ws;
  int* idx = (int*)ws;                                   // 1 MB
  float* WT = (float*)(ws + (1 << 20));                  // 66304 B
  float* featT = (float*)(ws + (1 << 20) + 66560);       // 32 MB
  const size_t need = (size_t)(1 << 20) + 66560 + (size_t)BQ * NPTS * CFEAT * 4;
  const bool useT = ws_size >= need;

  hipLaunchKernelGGL(prep_wt, dim3(64), dim3(256), 0, stream, W1, W2, W3, WT);
  hipLaunchKernelGGL(fps_kernel, dim3(BQ), dim3(1024), 0, stream, xyz, out_newxyz);
  if (useT)
    hipLaunchKernelGGL(transpose_kernel, dim3(NPTS / 64, BQ), dim3(256), 0, stream,
                       features, featT);
  hipLaunchKernelGGL(ballquery_kernel, dim3(BQ * NPOINT / 4), dim3(256), 0, stream,
                     xyz, out_newxyz, idx);
  if (useT)
    hipLaunchKernelGGL(mlp_kernel<true>, dim3(BQ * NPOINT), dim3(256), 0, stream,
                       xyz, features, featT, out_newxyz, idx, WT, b1, b2, b3, out_feat);
  else
    hipLaunchKernelGGL(mlp_kernel<false>, dim3(BQ * NPOINT), dim3(256), 0, stream,
                       xyz, features, featT, out_newxyz, idx, WT, b1, b2, b3, out_feat);
}

// Round 4
// 3306.841 us; speedup vs baseline: 1.1738x; 1.1738x over previous
//
#include <hip/hip_runtime.h>

#define BQ 8
#define NPTS 16384
#define CFEAT 64
#define NPOINT 1024
#define NSAMPLE 32
#define RADIUS2 0.04f

// ------------------------------------------------------------------
// Fused front kernel, 512 threads/block:
//   blocks 0..7   : furthest point sampling (1 block per batch)
//   block  8      : weight transpose prep
//   blocks 9..2056: features (B,C,N) -> featT (B,N,C) transpose
// FPS v2: 8 waves x 32 pts/thread in registers; ONE barrier per
// iteration (parity double-buffered wave-best table); every wave
// redundantly reduces the 8 wave-bests and fetches the winner's
// coords via scalar load -> no serial tail, no second barrier.
// fp contract OFF in FPS so fp32 matches numpy exactly (argmax cascade).
// ------------------------------------------------------------------
__global__ __launch_bounds__(512, 2) void fused_front_kernel(
    const float* __restrict__ xyz, const float* __restrict__ feat,
    const float* __restrict__ W1, const float* __restrict__ W2,
    const float* __restrict__ W3, float* __restrict__ WT,
    float* __restrict__ featT, float* __restrict__ newxyz) {
  __shared__ float s_val[2][8];
  __shared__ int s_idx[2][8];
  __shared__ float tile[64][65];
  const int blk = blockIdx.x;
  const int t = threadIdx.x;

  if (blk < 8) {
#pragma clang fp contract(off)
    const int b = blk;
    const float* xb = xyz + (size_t)b * NPTS * 3;
    float* nb = newxyz + (size_t)b * NPOINT * 3;
    float px[32], py[32], pz[32], dist[32];
#pragma unroll
    for (int k = 0; k < 32; ++k) {
      int p = (k << 9) | t;
      px[k] = xb[p * 3 + 0];
      py[k] = xb[p * 3 + 1];
      pz[k] = xb[p * 3 + 2];
      dist[k] = 1e10f;
    }
    float lx = xb[0], ly = xb[1], lz = xb[2];
    if (t == 0) { nb[0] = lx; nb[1] = ly; nb[2] = lz; }
    const int w = t >> 6;
    const int lane = t & 63;
    for (int j = 1; j < NPOINT; ++j) {
      float bestv = -1.0f;
      int bestk = 0;
#pragma unroll
      for (int k = 0; k < 32; ++k) {
        float dx = px[k] - lx, dy = py[k] - ly, dz = pz[k] - lz;
        float d = dx * dx + dy * dy;
        d = d + dz * dz;
        float nd = fminf(dist[k], d);
        dist[k] = nd;
        if (nd > bestv) { bestv = nd; bestk = k; }  // strict > keeps smallest k
      }
      int besti = (bestk << 9) | t;
      // wave-64 argmax butterfly, smallest-index tie break
#pragma unroll
      for (int off = 1; off < 64; off <<= 1) {
        float ov = __shfl_xor(bestv, off);
        int oi = __shfl_xor(besti, off);
        if (ov > bestv || (ov == bestv && oi < besti)) { bestv = ov; besti = oi; }
      }
      const int pw = j & 1;
      if (lane == 0) { s_val[pw][w] = bestv; s_idx[pw][w] = besti; }
      __syncthreads();
      // every wave reduces the 8 wave-bests (replicated across lanes)
      float v = s_val[pw][lane & 7];
      int vi = s_idx[pw][lane & 7];
#pragma unroll
      for (int off = 1; off < 8; off <<= 1) {
        float ov = __shfl_xor(v, off);
        int oi = __shfl_xor(vi, off);
        if (ov > v || (ov == v && oi < vi)) { v = ov; vi = oi; }
      }
      const int wi = __builtin_amdgcn_readfirstlane(vi);
      const float* p = xb + (size_t)wi * 3;
      lx = p[0]; ly = p[1]; lz = p[2];
      if (t == 0) { float* o = nb + j * 3; o[0] = lx; o[1] = ly; o[2] = lz; }
    }
  } else if (blk == 8) {
    // weight transposes: W*T[c][o] = W*[o][c]
    float* W1T = WT;                      // 67 x 64
    float* W2T = WT + 67 * 64;            // 64 x 64
    float* W3T = WT + 67 * 64 + 64 * 64;  // 64 x 128
    for (int i = t; i < 64 * 67; i += 512) { int o = i / 67, c = i - o * 67; W1T[c * 64 + o] = W1[i]; }
    for (int i = t; i < 64 * 64; i += 512) { int o = i >> 6, c = i & 63; W2T[c * 64 + o] = W2[i]; }
    for (int i = t; i < 128 * 64; i += 512) { int o = i >> 6, c = i & 63; W3T[c * 128 + o] = W3[i]; }
  } else {
    // feature transpose, one 64x64 tile per block
    const int tid = blk - 9;
    const int b = tid >> 8;
    const int n0 = (tid & 255) << 6;
    const int col = t & 63;
    const int row = t >> 6;  // 0..7
#pragma unroll
    for (int k = 0; k < 8; ++k) {
      int c = k * 8 + row;
      tile[c][col] = feat[((size_t)b * CFEAT + c) * NPTS + n0 + col];
    }
    __syncthreads();
#pragma unroll
    for (int k = 0; k < 8; ++k) {
      int nl = k * 8 + row;
      featT[((size_t)b * NPTS + n0 + nl) * CFEAT + col] = tile[col][nl];
    }
  }
}

// ------------------------------------------------------------------
// Ball query: 1 wave per query, 4 queries per 256-thread block.
// Scans all N points in index order via LDS tiles; ballot-compacts the
// first 32 indices with d2 <= r^2; pads remainder with first index.
// ------------------------------------------------------------------
__global__ __launch_bounds__(256) void ballquery_kernel(const float* __restrict__ xyz,
                                                        const float* __restrict__ newxyz,
                                                        int* __restrict__ idxout) {
#pragma clang fp contract(off)
  const int blk = blockIdx.x;
  const int b = blk >> 8;  // 256 blocks per batch
  const int t = threadIdx.x;
  const int w = t >> 6;
  const int lane = t & 63;
  const int q = ((blk & 255) << 2) | w;
  const int g = b * NPOINT + q;
  const float* xb = xyz + (size_t)b * NPTS * 3;
  const float qx = newxyz[(size_t)g * 3 + 0];
  const float qy = newxyz[(size_t)g * 3 + 1];
  const float qz = newxyz[(size_t)g * 3 + 2];
  __shared__ __align__(16) float lds[2048 * 3];
  int total = 0;
  int first = 0;
  const unsigned long long ltmask = (1ull << lane) - 1ull;
  for (int T = 0; T < 8; ++T) {
    __syncthreads();
    const float4* src = (const float4*)(xb + (size_t)T * 2048 * 3);
#pragma unroll
    for (int k = 0; k < 6; ++k) ((float4*)lds)[t + 256 * k] = src[t + 256 * k];
    __syncthreads();
    if (total < NSAMPLE) {
      for (int c = 0; c < 32; ++c) {
        const int il = (c << 6) | lane;
        float dx = lds[il * 3 + 0] - qx;
        float dy = lds[il * 3 + 1] - qy;
        float dz = lds[il * 3 + 2] - qz;
        float d2 = dx * dx + dy * dy;
        d2 = d2 + dz * dz;
        const bool within = d2 <= RADIUS2;
        const unsigned long long mask = __ballot(within);
        if (total == 0 && mask != 0ull)
          first = (T << 11) | (c << 6) | (__ffsll((unsigned long long)mask) - 1);
        if (within) {
          int pos = total + __popcll(mask & ltmask);
          if (pos < NSAMPLE) idxout[(size_t)g * NSAMPLE + pos] = (T << 11) | il;
        }
        total += __popcll(mask);
        if (total >= NSAMPLE) break;
      }
    }
  }
  if (total < NSAMPLE) {
    if (lane >= total && lane < NSAMPLE) idxout[(size_t)g * NSAMPLE + lane] = first;
  }
}

// ------------------------------------------------------------------
// Gather + 3-layer pointwise MLP + max over 32 samples. One block per
// group (b,q): 256 threads = 32 samples x 8 lanes. Hidden activations
// staged in LDS (padded strides 69/132 -> conflict-free).
// ------------------------------------------------------------------
template <bool USE_FEATT>
__global__ __launch_bounds__(256) void mlp_kernel(const float* __restrict__ xyz,
                                                  const float* __restrict__ feat,
                                                  const float* __restrict__ featT,
                                                  const float* __restrict__ newxyz,
                                                  const int* __restrict__ idx,
                                                  const float* __restrict__ WT,
                                                  const float* __restrict__ b1,
                                                  const float* __restrict__ b2,
                                                  const float* __restrict__ b3,
                                                  float* __restrict__ outfeat) {
  const int g = blockIdx.x;
  const int b = g >> 10;
  const int q = g & 1023;
  const int t = threadIdx.x;
  const int s = t >> 3;
  const int u = t & 7;
  __shared__ float in_s[32][69];
  __shared__ float h1_s[32][69];
  __shared__ float h2_s[32][69];
  __shared__ float h3_s[32][132];
  const float* W1T = WT;
  const float* W2T = WT + 67 * 64;
  const float* W3T = WT + 67 * 64 + 64 * 64;

  const int gi = idx[(size_t)g * NSAMPLE + s];
  if (u == 0) {
    const float* p = xyz + ((size_t)b * NPTS + gi) * 3;
    const float* c = newxyz + (size_t)g * 3;
    in_s[s][0] = p[0] - c[0];
    in_s[s][1] = p[1] - c[1];
    in_s[s][2] = p[2] - c[2];
  }
  if (USE_FEATT) {
    const float* fr = featT + ((size_t)b * NPTS + gi) * CFEAT + u * 8;
    float4 a = *(const float4*)fr;
    float4 c4 = *(const float4*)(fr + 4);
    in_s[s][3 + u * 8 + 0] = a.x;  in_s[s][3 + u * 8 + 1] = a.y;
    in_s[s][3 + u * 8 + 2] = a.z;  in_s[s][3 + u * 8 + 3] = a.w;
    in_s[s][3 + u * 8 + 4] = c4.x; in_s[s][3 + u * 8 + 5] = c4.y;
    in_s[s][3 + u * 8 + 6] = c4.z; in_s[s][3 + u * 8 + 7] = c4.w;
  } else {
#pragma unroll
    for (int k = 0; k < 8; ++k)
      in_s[s][3 + u * 8 + k] = feat[((size_t)b * CFEAT + u * 8 + k) * NPTS + gi];
  }
  __syncthreads();
  {  // layer 1: 67 -> 64
    float acc[8];
    const int o0 = u * 8;
#pragma unroll
    for (int k = 0; k < 8; ++k) acc[k] = b1[o0 + k];
    for (int c = 0; c < 67; ++c) {
      float x = in_s[s][c];
      const float* wp = W1T + c * 64 + o0;
      float4 w0 = *(const float4*)wp;
      float4 w1 = *(const float4*)(wp + 4);
      acc[0] += w0.x * x; acc[1] += w0.y * x; acc[2] += w0.z * x; acc[3] += w0.w * x;
      acc[4] += w1.x * x; acc[5] += w1.y * x; acc[6] += w1.z * x; acc[7] += w1.w * x;
    }
#pragma unroll
    for (int k = 0; k < 8; ++k) h1_s[s][o0 + k] = fmaxf(acc[k], 0.0f);
  }
  __syncthreads();
  {  // layer 2: 64 -> 64
    float acc[8];
    const int o0 = u * 8;
#pragma unroll
    for (int k = 0; k < 8; ++k) acc[k] = b2[o0 + k];
    for (int c = 0; c < 64; ++c) {
      float x = h1_s[s][c];
      const float* wp = W2T + c * 64 + o0;
      float4 w0 = *(const float4*)wp;
      float4 w1 = *(const float4*)(wp + 4);
      acc[0] += w0.x * x; acc[1] += w0.y * x; acc[2] += w0.z * x; acc[3] += w0.w * x;
      acc[4] += w1.x * x; acc[5] += w1.y * x; acc[6] += w1.z * x; acc[7] += w1.w * x;
    }
#pragma unroll
    for (int k = 0; k < 8; ++k) h2_s[s][o0 + k] = fmaxf(acc[k], 0.0f);
  }
  __syncthreads();
  {  // layer 3: 64 -> 128
    float acc[16];
    const int o0 = u * 16;
#pragma unroll
    for (int k = 0; k < 16; ++k) acc[k] = b3[o0 + k];
    for (int c = 0; c < 64; ++c) {
      float x = h2_s[s][c];
      const float* wp = W3T + c * 128 + o0;
      float4 w0 = *(const float4*)wp;
      float4 w1 = *(const float4*)(wp + 4);
      float4 w2 = *(const float4*)(wp + 8);
      float4 w3 = *(const float4*)(wp + 12);
      acc[0] += w0.x * x;  acc[1] += w0.y * x;  acc[2] += w0.z * x;  acc[3] += w0.w * x;
      acc[4] += w1.x * x;  acc[5] += w1.y * x;  acc[6] += w1.z * x;  acc[7] += w1.w * x;
      acc[8] += w2.x * x;  acc[9] += w2.y * x;  acc[10] += w2.z * x; acc[11] += w2.w * x;
      acc[12] += w3.x * x; acc[13] += w3.y * x; acc[14] += w3.z * x; acc[15] += w3.w * x;
    }
#pragma unroll
    for (int k = 0; k < 16; ++k) h3_s[s][o0 + k] = fmaxf(acc[k], 0.0f);
  }
  __syncthreads();
  if (t < 128) {
    float m = h3_s[0][t];
#pragma unroll 4
    for (int ss = 1; ss < 32; ++ss) m = fmaxf(m, h3_s[ss][t]);
    outfeat[((size_t)b * 128 + t) * NPOINT + q] = m;
  }
}

extern "C" void kernel_launch(void* const* d_in, const int* in_sizes, int n_in,
                              void* d_out, int out_size, void* d_ws, size_t ws_size,
                              hipStream_t stream) {
  const float* xyz = (const float*)d_in[0];
  const float* features = (const float*)d_in[1];
  const float* W1 = (const float*)d_in[2];
  const float* b1 = (const float*)d_in[3];
  const float* W2 = (const float*)d_in[4];
  const float* b2 = (const float*)d_in[5];
  const float* W3 = (const float*)d_in[6];
  const float* b3 = (const float*)d_in[7];
  float* out_newxyz = (float*)d_out;                          // B*NPOINT*3
  float* out_feat = (float*)d_out + (size_t)BQ * NPOINT * 3;  // B*128*NPOINT

  char* ws = (char*)d_ws;
  int* idx = (int*)ws;                              // 1 MB
  float* WT = (float*)(ws + (1 << 20));             // 66304 B
  float* featT = (float*)(ws + (1 << 20) + 66560);  // 32 MB
  const size_t need = (size_t)(1 << 20) + 66560 + (size_t)BQ * NPTS * CFEAT * 4;
  const bool useT = ws_size >= need;

  const int nfront = useT ? (9 + (NPTS / 64) * BQ) : 9;
  hipLaunchKernelGGL(fused_front_kernel, dim3(nfront), dim3(512), 0, stream,
                     xyz, features, W1, W2, W3, WT, featT, out_newxyz);
  hipLaunchKernelGGL(ballquery_kernel, dim3(BQ * NPOINT / 4), dim3(256), 0, stream,
                     xyz, out_newxyz, idx);
  if (useT)
    hipLaunchKernelGGL(mlp_kernel<true>, dim3(BQ * NPOINT), dim3(256), 0, stream,
                       xyz, features, featT, out_newxyz, idx, WT, b1, b2, b3, out_feat);
  else
    hipLaunchKernelGGL(mlp_kernel<false>, dim3(BQ * NPOINT), dim3(256), 0, stream,
                       xyz, features, featT, out_newxyz, idx, WT, b1, b2, b3, out_feat);
}

// Round 5
// 3282.307 us; speedup vs baseline: 1.1825x; 1.0075x over previous
//
#include <hip/hip_runtime.h>

#define BQ 8
#define NPTS 16384
#define CFEAT 64
#define NPOINT 1024
#define NSAMPLE 32
#define RADIUS2 0.04f

typedef float v2f __attribute__((ext_vector_type(2)));

// ------------------------------------------------------------------
// Fused front kernel, 512 threads/block:
//   blocks 0..7   : furthest point sampling (1 block per batch)
//   block  8      : weight transpose prep
//   blocks 9..2056: features (B,C,N) -> featT (B,N,C) transpose
// FPS v3: 8 waves x 32 pts/thread held as 16 float2 pairs; asm "+v"
// pins inside the loop stop the compiler rematerializing the coord
// loads (round-4 pathology: VGPR_Count=84 < 128 live floats needed).
// Packed float2 math lets the backend emit v_pk_add/mul_f32 (IEEE-
// identical per lane). One barrier per iteration; every wave
// redundantly reduces the 8 wave-bests; winner coords via scalar load.
// fp contract OFF so fp32 matches numpy exactly (argmax cascade).
// ------------------------------------------------------------------
__global__ __launch_bounds__(512, 2) void fused_front_kernel(
    const float* __restrict__ xyz, const float* __restrict__ feat,
    const float* __restrict__ W1, const float* __restrict__ W2,
    const float* __restrict__ W3, float* __restrict__ WT,
    float* __restrict__ featT, float* __restrict__ newxyz) {
  __shared__ float s_val[2][8];
  __shared__ int s_idx[2][8];
  __shared__ float tile[64][65];
  const int blk = blockIdx.x;
  const int t = threadIdx.x;

  if (blk < 8) {
#pragma clang fp contract(off)
    const int b = blk;
    const float* xb = xyz + (size_t)b * NPTS * 3;
    float* nb = newxyz + (size_t)b * NPOINT * 3;
    v2f px[16], py[16], pz[16], dd[16];
#pragma unroll
    for (int k = 0; k < 16; ++k) {
      const int pa = ((2 * k) << 9) | t;
      const int pb = ((2 * k + 1) << 9) | t;
      v2f x, y, z, d0;
      x.x = xb[pa * 3 + 0]; x.y = xb[pb * 3 + 0];
      y.x = xb[pa * 3 + 1]; y.y = xb[pb * 3 + 1];
      z.x = xb[pa * 3 + 2]; z.y = xb[pb * 3 + 2];
      d0.x = 1e10f; d0.y = 1e10f;
      px[k] = x; py[k] = y; pz[k] = z; dd[k] = d0;
    }
    float lx = xb[0], ly = xb[1], lz = xb[2];
    if (t == 0) { nb[0] = lx; nb[1] = ly; nb[2] = lz; }
    const int w = t >> 6;
    const int lane = t & 63;
    for (int j = 1; j < NPOINT; ++j) {
      // liveness pins: forbid remat/reload of the coord registers
      asm volatile("" : "+v"(px[0]), "+v"(px[1]), "+v"(px[2]), "+v"(px[3]),
                         "+v"(px[4]), "+v"(px[5]), "+v"(px[6]), "+v"(px[7]),
                         "+v"(px[8]), "+v"(px[9]), "+v"(px[10]), "+v"(px[11]),
                         "+v"(px[12]), "+v"(px[13]), "+v"(px[14]), "+v"(px[15]));
      asm volatile("" : "+v"(py[0]), "+v"(py[1]), "+v"(py[2]), "+v"(py[3]),
                         "+v"(py[4]), "+v"(py[5]), "+v"(py[6]), "+v"(py[7]),
                         "+v"(py[8]), "+v"(py[9]), "+v"(py[10]), "+v"(py[11]),
                         "+v"(py[12]), "+v"(py[13]), "+v"(py[14]), "+v"(py[15]));
      asm volatile("" : "+v"(pz[0]), "+v"(pz[1]), "+v"(pz[2]), "+v"(pz[3]),
                         "+v"(pz[4]), "+v"(pz[5]), "+v"(pz[6]), "+v"(pz[7]),
                         "+v"(pz[8]), "+v"(pz[9]), "+v"(pz[10]), "+v"(pz[11]),
                         "+v"(pz[12]), "+v"(pz[13]), "+v"(pz[14]), "+v"(pz[15]));
      v2f l2x, l2y, l2z;
      l2x.x = lx; l2x.y = lx;
      l2y.x = ly; l2y.y = ly;
      l2z.x = lz; l2z.y = lz;
      float bestv = -1.0f;
      int bestK = 0;
#pragma unroll
      for (int k = 0; k < 16; ++k) {
        v2f dx = px[k] - l2x, dy = py[k] - l2y, dz = pz[k] - l2z;
        v2f s = dx * dx + dy * dy;   // contract off: pk_mul, pk_mul, pk_add
        s = s + dz * dz;
        float n0 = fminf(dd[k].x, s.x);
        float n1 = fminf(dd[k].y, s.y);
        dd[k].x = n0; dd[k].y = n1;
        if (n0 > bestv) { bestv = n0; bestK = 2 * k; }      // .x first: K ascending,
        if (n1 > bestv) { bestv = n1; bestK = 2 * k + 1; }  // strict > keeps smallest K
      }
      int besti = (bestK << 9) | t;
      // wave-64 argmax butterfly, smallest-index tie break
#pragma unroll
      for (int off = 1; off < 64; off <<= 1) {
        float ov = __shfl_xor(bestv, off);
        int oi = __shfl_xor(besti, off);
        if (ov > bestv || (ov == bestv && oi < besti)) { bestv = ov; besti = oi; }
      }
      const int pw = j & 1;
      if (lane == 0) { s_val[pw][w] = bestv; s_idx[pw][w] = besti; }
      __syncthreads();
      // every wave reduces the 8 wave-bests (replicated across lanes)
      float v = s_val[pw][lane & 7];
      int vi = s_idx[pw][lane & 7];
#pragma unroll
      for (int off = 1; off < 8; off <<= 1) {
        float ov = __shfl_xor(v, off);
        int oi = __shfl_xor(vi, off);
        if (ov > v || (ov == v && oi < vi)) { v = ov; vi = oi; }
      }
      const int wi = __builtin_amdgcn_readfirstlane(vi);
      const float* p = xb + (size_t)wi * 3;
      lx = p[0]; ly = p[1]; lz = p[2];
      if (t == 0) { float* o = nb + j * 3; o[0] = lx; o[1] = ly; o[2] = lz; }
    }
  } else if (blk == 8) {
    // weight transposes: W*T[c][o] = W*[o][c]
    float* W1T = WT;                      // 67 x 64
    float* W2T = WT + 67 * 64;            // 64 x 64
    float* W3T = WT + 67 * 64 + 64 * 64;  // 64 x 128
    for (int i = t; i < 64 * 67; i += 512) { int o = i / 67, c = i - o * 67; W1T[c * 64 + o] = W1[i]; }
    for (int i = t; i < 64 * 64; i += 512) { int o = i >> 6, c = i & 63; W2T[c * 64 + o] = W2[i]; }
    for (int i = t; i < 128 * 64; i += 512) { int o = i >> 6, c = i & 63; W3T[c * 128 + o] = W3[i]; }
  } else {
    // feature transpose, one 64x64 tile per block
    const int tid = blk - 9;
    const int b = tid >> 8;
    const int n0 = (tid & 255) << 6;
    const int col = t & 63;
    const int row = t >> 6;  // 0..7
#pragma unroll
    for (int k = 0; k < 8; ++k) {
      int c = k * 8 + row;
      tile[c][col] = feat[((size_t)b * CFEAT + c) * NPTS + n0 + col];
    }
    __syncthreads();
#pragma unroll
    for (int k = 0; k < 8; ++k) {
      int nl = k * 8 + row;
      featT[((size_t)b * NPTS + n0 + nl) * CFEAT + col] = tile[col][nl];
    }
  }
}

// ------------------------------------------------------------------
// Ball query: 1 wave per query, 4 queries per 256-thread block.
// Scans all N points in index order via LDS tiles; ballot-compacts the
// first 32 indices with d2 <= r^2; pads remainder with first index.
// ------------------------------------------------------------------
__global__ __launch_bounds__(256) void ballquery_kernel(const float* __restrict__ xyz,
                                                        const float* __restrict__ newxyz,
                                                        int* __restrict__ idxout) {
#pragma clang fp contract(off)
  const int blk = blockIdx.x;
  const int b = blk >> 8;  // 256 blocks per batch
  const int t = threadIdx.x;
  const int w = t >> 6;
  const int lane = t & 63;
  const int q = ((blk & 255) << 2) | w;
  const int g = b * NPOINT + q;
  const float* xb = xyz + (size_t)b * NPTS * 3;
  const float qx = newxyz[(size_t)g * 3 + 0];
  const float qy = newxyz[(size_t)g * 3 + 1];
  const float qz = newxyz[(size_t)g * 3 + 2];
  __shared__ __align__(16) float lds[2048 * 3];
  int total = 0;
  int first = 0;
  const unsigned long long ltmask = (1ull << lane) - 1ull;
  for (int T = 0; T < 8; ++T) {
    __syncthreads();
    const float4* src = (const float4*)(xb + (size_t)T * 2048 * 3);
#pragma unroll
    for (int k = 0; k < 6; ++k) ((float4*)lds)[t + 256 * k] = src[t + 256 * k];
    __syncthreads();
    if (total < NSAMPLE) {
      for (int c = 0; c < 32; ++c) {
        const int il = (c << 6) | lane;
        float dx = lds[il * 3 + 0] - qx;
        float dy = lds[il * 3 + 1] - qy;
        float dz = lds[il * 3 + 2] - qz;
        float d2 = dx * dx + dy * dy;
        d2 = d2 + dz * dz;
        const bool within = d2 <= RADIUS2;
        const unsigned long long mask = __ballot(within);
        if (total == 0 && mask != 0ull)
          first = (T << 11) | (c << 6) | (__ffsll((unsigned long long)mask) - 1);
        if (within) {
          int pos = total + __popcll(mask & ltmask);
          if (pos < NSAMPLE) idxout[(size_t)g * NSAMPLE + pos] = (T << 11) | il;
        }
        total += __popcll(mask);
        if (total >= NSAMPLE) break;
      }
    }
  }
  if (total < NSAMPLE) {
    if (lane >= total && lane < NSAMPLE) idxout[(size_t)g * NSAMPLE + lane] = first;
  }
}

// ------------------------------------------------------------------
// Gather + 3-layer pointwise MLP + max over 32 samples. One block per
// group (b,q): 256 threads = 32 samples x 8 lanes. Hidden activations
// staged in LDS (padded strides 69/132 -> conflict-free).
// ------------------------------------------------------------------
template <bool USE_FEATT>
__global__ __launch_bounds__(256) void mlp_kernel(const float* __restrict__ xyz,
                                                  const float* __restrict__ feat,
                                                  const float* __restrict__ featT,
                                                  const float* __restrict__ newxyz,
                                                  const int* __restrict__ idx,
                                                  const float* __restrict__ WT,
                                                  const float* __restrict__ b1,
                                                  const float* __restrict__ b2,
                                                  const float* __restrict__ b3,
                                                  float* __restrict__ outfeat) {
  const int g = blockIdx.x;
  const int b = g >> 10;
  const int q = g & 1023;
  const int t = threadIdx.x;
  const int s = t >> 3;
  const int u = t & 7;
  __shared__ float in_s[32][69];
  __shared__ float h1_s[32][69];
  __shared__ float h2_s[32][69];
  __shared__ float h3_s[32][132];
  const float* W1T = WT;
  const float* W2T = WT + 67 * 64;
  const float* W3T = WT + 67 * 64 + 64 * 64;

  const int gi = idx[(size_t)g * NSAMPLE + s];
  if (u == 0) {
    const float* p = xyz + ((size_t)b * NPTS + gi) * 3;
    const float* c = newxyz + (size_t)g * 3;
    in_s[s][0] = p[0] - c[0];
    in_s[s][1] = p[1] - c[1];
    in_s[s][2] = p[2] - c[2];
  }
  if (USE_FEATT) {
    const float* fr = featT + ((size_t)b * NPTS + gi) * CFEAT + u * 8;
    float4 a = *(const float4*)fr;
    float4 c4 = *(const float4*)(fr + 4);
    in_s[s][3 + u * 8 + 0] = a.x;  in_s[s][3 + u * 8 + 1] = a.y;
    in_s[s][3 + u * 8 + 2] = a.z;  in_s[s][3 + u * 8 + 3] = a.w;
    in_s[s][3 + u * 8 + 4] = c4.x; in_s[s][3 + u * 8 + 5] = c4.y;
    in_s[s][3 + u * 8 + 6] = c4.z; in_s[s][3 + u * 8 + 7] = c4.w;
  } else {
#pragma unroll
    for (int k = 0; k < 8; ++k)
      in_s[s][3 + u * 8 + k] = feat[((size_t)b * CFEAT + u * 8 + k) * NPTS + gi];
  }
  __syncthreads();
  {  // layer 1: 67 -> 64
    float acc[8];
    const int o0 = u * 8;
#pragma unroll
    for (int k = 0; k < 8; ++k) acc[k] = b1[o0 + k];
    for (int c = 0; c < 67; ++c) {
      float x = in_s[s][c];
      const float* wp = W1T + c * 64 + o0;
      float4 w0 = *(const float4*)wp;
      float4 w1 = *(const float4*)(wp + 4);
      acc[0] += w0.x * x; acc[1] += w0.y * x; acc[2] += w0.z * x; acc[3] += w0.w * x;
      acc[4] += w1.x * x; acc[5] += w1.y * x; acc[6] += w1.z * x; acc[7] += w1.w * x;
    }
#pragma unroll
    for (int k = 0; k < 8; ++k) h1_s[s][o0 + k] = fmaxf(acc[k], 0.0f);
  }
  __syncthreads();
  {  // layer 2: 64 -> 64
    float acc[8];
    const int o0 = u * 8;
#pragma unroll
    for (int k = 0; k < 8; ++k) acc[k] = b2[o0 + k];
    for (int c = 0; c < 64; ++c) {
      float x = h1_s[s][c];
      const float* wp = W2T + c * 64 + o0;
      float4 w0 = *(const float4*)wp;
      float4 w1 = *(const float4*)(wp + 4);
      acc[0] += w0.x * x; acc[1] += w0.y * x; acc[2] += w0.z * x; acc[3] += w0.w * x;
      acc[4] += w1.x * x; acc[5] += w1.y * x; acc[6] += w1.z * x; acc[7] += w1.w * x;
    }
#pragma unroll
    for (int k = 0; k < 8; ++k) h2_s[s][o0 + k] = fmaxf(acc[k], 0.0f);
  }
  __syncthreads();
  {  // layer 3: 64 -> 128
    float acc[16];
    const int o0 = u * 16;
#pragma unroll
    for (int k = 0; k < 16; ++k) acc[k] = b3[o0 + k];
    for (int c = 0; c < 64; ++c) {
      float x = h2_s[s][c];
      const float* wp = W3T + c * 128 + o0;
      float4 w0 = *(const float4*)wp;
      float4 w1 = *(const float4*)(wp + 4);
      float4 w2 = *(const float4*)(wp + 8);
      float4 w3 = *(const float4*)(wp + 12);
      acc[0] += w0.x * x;  acc[1] += w0.y * x;  acc[2] += w0.z * x;  acc[3] += w0.w * x;
      acc[4] += w1.x * x;  acc[5] += w1.y * x;  acc[6] += w1.z * x;  acc[7] += w1.w * x;
      acc[8] += w2.x * x;  acc[9] += w2.y * x;  acc[10] += w2.z * x; acc[11] += w2.w * x;
      acc[12] += w3.x * x; acc[13] += w3.y * x; acc[14] += w3.z * x; acc[15] += w3.w * x;
    }
#pragma unroll
    for (int k = 0; k < 16; ++k) h3_s[s][o0 + k] = fmaxf(acc[k], 0.0f);
  }
  __syncthreads();
  if (t < 128) {
    float m = h3_s[0][t];
#pragma unroll 4
    for (int ss = 1; ss < 32; ++ss) m = fmaxf(m, h3_s[ss][t]);
    outfeat[((size_t)b * 128 + t) * NPOINT + q] = m;
  }
}

extern "C" void kernel_launch(void* const* d_in, const int* in_sizes, int n_in,
                              void* d_out, int out_size, void* d_ws, size_t ws_size,
                              hipStream_t stream) {
  const float* xyz = (const float*)d_in[0];
  const float* features = (const float*)d_in[1];
  const float* W1 = (const float*)d_in[2];
  const float* b1 = (const float*)d_in[3];
  const float* W2 = (const float*)d_in[4];
  const float* b2 = (const float*)d_in[5];
  const float* W3 = (const float*)d_in[6];
  const float* b3 = (const float*)d_in[7];
  float* out_newxyz = (float*)d_out;                          // B*NPOINT*3
  float* out_feat = (float*)d_out + (size_t)BQ * NPOINT * 3;  // B*128*NPOINT

  char* ws = (char*)d_ws;
  int* idx = (int*)ws;                              // 1 MB
  float* WT = (float*)(ws + (1 << 20));             // 66304 B
  float* featT = (float*)(ws + (1 << 20) + 66560);  // 32 MB
  const size_t need = (size_t)(1 << 20) + 66560 + (size_t)BQ * NPTS * CFEAT * 4;
  const bool useT = ws_size >= need;

  const int nfront = useT ? (9 + (NPTS / 64) * BQ) : 9;
  hipLaunchKernelGGL(fused_front_kernel, dim3(nfront), dim3(512), 0, stream,
                     xyz, features, W1, W2, W3, WT, featT, out_newxyz);
  hipLaunchKernelGGL(ballquery_kernel, dim3(BQ * NPOINT / 4), dim3(256), 0, stream,
                     xyz, out_newxyz, idx);
  if (useT)
    hipLaunchKernelGGL(mlp_kernel<true>, dim3(BQ * NPOINT), dim3(256), 0, stream,
                       xyz, features, featT, out_newxyz, idx, WT, b1, b2, b3, out_feat);
  else
    hipLaunchKernelGGL(mlp_kernel<false>, dim3(BQ * NPOINT), dim3(256), 0, stream,
                       xyz, features, featT, out_newxyz, idx, WT, b1, b2, b3, out_feat);
}